// Round 3
// baseline (1026.817 us; speedup 1.0000x reference)
//
#include <hip/hip_runtime.h>
#include <cstdint>
#include <cstddef>

#define B_    8192
#define L_    1000
#define NPAIR 4950
#define NG    5      // h7 pair groups
#define PG    990    // pairs per group (5*990 = 4950, even)

// Opaque-ize a pointer into VGPRs so the compiler cannot prove wave-uniformity
// and scalarize the load into s_load (SMEM drains serialized the round-2 kernel).
__device__ __forceinline__ const float* vop(const float* p) {
    asm volatile("" : "+v"(p));
    return p;
}

__device__ __forceinline__ void load7(const float* p, float4 q[7]) {
    const float4* p4 = (const float4*)vop(p);
    #pragma unroll
    for (int t = 0; t < 7; t++) q[t] = p4[t];
}

__device__ __forceinline__ void load8(const float* p, float4 q[8]) {
    const float4* p4 = (const float4*)vop(p);
    #pragma unroll
    for (int t = 0; t < 8; t++) q[t] = p4[t];
}

__device__ __forceinline__ void fma25(float* acc, float v, const float4 q[7]) {
    acc[0]  = fmaf(v, q[0].x, acc[0]);  acc[1]  = fmaf(v, q[0].y, acc[1]);
    acc[2]  = fmaf(v, q[0].z, acc[2]);  acc[3]  = fmaf(v, q[0].w, acc[3]);
    acc[4]  = fmaf(v, q[1].x, acc[4]);  acc[5]  = fmaf(v, q[1].y, acc[5]);
    acc[6]  = fmaf(v, q[1].z, acc[6]);  acc[7]  = fmaf(v, q[1].w, acc[7]);
    acc[8]  = fmaf(v, q[2].x, acc[8]);  acc[9]  = fmaf(v, q[2].y, acc[9]);
    acc[10] = fmaf(v, q[2].z, acc[10]); acc[11] = fmaf(v, q[2].w, acc[11]);
    acc[12] = fmaf(v, q[3].x, acc[12]); acc[13] = fmaf(v, q[3].y, acc[13]);
    acc[14] = fmaf(v, q[3].z, acc[14]); acc[15] = fmaf(v, q[3].w, acc[15]);
    acc[16] = fmaf(v, q[4].x, acc[16]); acc[17] = fmaf(v, q[4].y, acc[17]);
    acc[18] = fmaf(v, q[4].z, acc[18]); acc[19] = fmaf(v, q[4].w, acc[19]);
    acc[20] = fmaf(v, q[5].x, acc[20]); acc[21] = fmaf(v, q[5].y, acc[21]);
    acc[22] = fmaf(v, q[5].z, acc[22]); acc[23] = fmaf(v, q[5].w, acc[23]);
    acc[24] = fmaf(v, q[6].x, acc[24]);
}

__device__ __forceinline__ void fma32(float* acc, float v, const float4 q[8]) {
    #pragma unroll
    for (int t = 0; t < 8; t++) {
        acc[4*t+0] = fmaf(v, q[t].x, acc[4*t+0]);
        acc[4*t+1] = fmaf(v, q[t].y, acc[4*t+1]);
        acc[4*t+2] = fmaf(v, q[t].z, acc[4*t+2]);
        acc[4*t+3] = fmaf(v, q[t].w, acc[4*t+3]);
    }
}

// ---------------- k0: all weight prep in ONE launch (255 blocks) ----------------
__global__ __launch_bounds__(256) void k0(const float* __restrict__ v,
        const float* __restrict__ W1, const float* __restrict__ b1, const float* __restrict__ W2,
        const float* __restrict__ W3, const float* __restrict__ b3, const float* __restrict__ W4,
        const float* __restrict__ W5, const float* __restrict__ W6, const float* __restrict__ W7,
        const float* __restrict__ b6, const float* __restrict__ b7,
        const float* __restrict__ W8, const float* __restrict__ b8,
        float* __restrict__ W7fT, float* __restrict__ W5fT, float* __restrict__ W86fT,
        float* __restrict__ W8bfT, float* __restrict__ usf, float* __restrict__ csf,
        float* __restrict__ bb8) {
    int blk = blockIdx.x, tid = threadIdx.x;
    if (blk < 78) {
        // W7fT[kq][p][28] = W7[kq*25+m][p] * vv(p); 64 pairs per block
        int p0 = blk * 64;
        for (int it = 0; it < 25; it++) {
            int o = it * 256 + tid;                  // 64*100
            int pl = o / 100, k = o - pl * 100;
            int p = p0 + pl;
            if (p < NPAIR) {
                int rem = p, len = 99;
                while (rem >= len) { rem -= len; len--; }
                int i = 99 - len; int j = i + 1 + rem;
                float vv = v[i*4+0]*v[j*4+0] + v[i*4+1]*v[j*4+1]
                         + v[i*4+2]*v[j*4+2] + v[i*4+3]*v[j*4+3];
                int kq = k / 25, m = k - kq * 25;
                W7fT[((size_t)kq * NPAIR + p) * 28 + m] = W7[(size_t)k * NPAIR + p] * vv;
            }
        }
    } else if (blk < 166) {
        // W5fT[kq][j][28] = W5[kq*25+m][j]
        int o = (blk - 78) * 256 + tid;              // 4*200*28 = 22400
        if (o < 22400) {
            int kq = o / 5600; int r = o - kq * 5600; int j = r / 28; int m = r - j * 28;
            W5fT[o] = (m < 25) ? W5[(kq * 25 + m) * 200 + j] : 0.f;
        }
    } else if (blk < 210) {
        // W86fT[kq][e][28] = sum_e2 W8[u][e2]*W6[e2][e],  u = kq*25+m
        int o = (blk - 166) * 256 + tid;             // 4*100*28 = 11200
        if (o < 11200) {
            int kq = o / 2800; int r = o - kq * 2800; int e = r / 28; int m = r - e * 28;
            float s = 0.f;
            if (m < 25) {
                int u = kq * 25 + m;
                for (int e2 = 0; e2 < 100; e2++) s = fmaf(W8[u * 200 + e2], W6[e2 * 100 + e], s);
            }
            W86fT[o] = s;
        }
    } else if (blk < 254) {
        // W8bfT[kq][e][28] = W8[kq*25+m][100+e]
        int o = (blk - 210) * 256 + tid;
        if (o < 11200) {
            int kq = o / 2800; int r = o - kq * 2800; int e = r / 28; int m = r - e * 28;
            W8bfT[o] = (m < 25) ? W8[(kq * 25 + m) * 200 + 100 + e] : 0.f;
        }
    } else {
        if (tid < 200) {
            int h = (tid >= 100); int e = tid - 100 * h;
            const float* Wa = h ? W3 : W1; const float* Wb = h ? W4 : W2;
            float u = 0.f;
            for (int t = 0; t < 8; t++) u += Wa[t * 100 + e] * Wb[t];
            usf[tid] = u;
        } else if (tid < 202) {
            int h = tid - 200;
            const float* bbv = h ? b3 : b1; const float* Wb = h ? W4 : W2;
            float c = 0.f;
            for (int t = 0; t < 8; t++) c += bbv[t] * Wb[t];
            csf[h] = c;
        }
        if (tid < 100) {
            // bb8[u] = b8[u] + W8a@b6 + W8b@b7   (b6,b7,b8 folded out of the pipeline)
            float s = b8[tid];
            for (int e = 0; e < 100; e++)
                s = fmaf(W8[tid * 200 + e], b6[e], fmaf(W8[tid * 200 + 100 + e], b7[e], s));
            bb8[tid] = s;
        }
    }
}

// ---------------- k1: attention pools -> cat1T[200][B] ----------------
__global__ __launch_bounds__(256) void k1(const float* __restrict__ x, const float* __restrict__ usf,
                                          const float* __restrict__ csf, float* __restrict__ cat1T) {
    __shared__ float xs[50 * 101];
    __shared__ float uss[200];
    __shared__ float part[256];
    __shared__ float zs[2][64];
    __shared__ float wsm[2][64];
    __shared__ float css[2];
    int b = blockIdx.x, tid = threadIdx.x;
    const float* xr = x + (size_t)b * 5000;
    for (int li = tid; li < 1250; li += 256) {
        float4 q = ((const float4*)xr)[li];
        int flat = li * 4; int n = flat / 100, e = flat - n * 100;
        float* d = xs + n * 101 + e;
        d[0] = q.x; d[1] = q.y; d[2] = q.z; d[3] = q.w;
    }
    if (tid < 200) uss[tid] = usf[tid];
    if (tid < 2) css[tid] = csf[tid];
    __syncthreads();
    // dots with 200 threads: tid -> h=tid&1, q=(tid>>1)&1 (e-half), n=tid>>2
    if (tid < 200) {
        int h = tid & 1, q = (tid >> 1) & 1, n = tid >> 2;
        const float* u = uss + h * 100 + q * 50;
        const float* xv = xs + n * 101 + q * 50;
        float s = 0.f;
        for (int e = 0; e < 50; e++) s = fmaf(xv[e], u[e], s);
        part[tid] = s;
    }
    __syncthreads();
    if (tid < 100) {
        int h = tid & 1, n = tid >> 1;
        float z = css[h] + part[(n << 2) | h] + part[(n << 2) | 2 | h];
        zs[h][n] = expf(z);                         // logits = exp(h @ Wb^T)
    }
    __syncthreads();
    int wv = tid >> 6, ln = tid & 63;
    if (wv < 2) {
        float a = (ln < 50) ? zs[wv][ln] : -3.0e38f;
        float m = a;
        for (int s = 1; s < 64; s <<= 1) m = fmaxf(m, __shfl_xor(m, s, 64));
        float ex = (ln < 50) ? expf(a - m) : 0.f;
        float ss = ex;
        for (int s = 1; s < 64; s <<= 1) ss += __shfl_xor(ss, s, 64);
        if (ln < 50) wsm[wv][ln] = ex / ss;         // softmax over N of the logits
    }
    __syncthreads();
    if (tid < 200) {
        int h = (tid >= 100); int e = tid - 100 * h;
        const float* wp = wsm[h];
        float s = 0.f;
        for (int n = 0; n < 50; n++) s = fmaf(xs[n * 101 + e], wp[n], s);
        cat1T[(size_t)tid * B_ + b] = s;            // transposed for k15 coalescing
    }
}

// ---------------- k15: h5T[100][B] = W5 @ cat1 + b5 (per-wave 25-k slice) ----------------
__global__ __launch_bounds__(64) void k15(const float* __restrict__ cat1T, const float* __restrict__ W5fT,
                                          const float* __restrict__ b5, float* __restrict__ h5T) {
    int rb = blockIdx.x >> 2, kq = blockIdx.x & 3;
    int lane = threadIdx.x;
    int c = rb * 64 + lane;
    const float* wbase = W5fT + kq * 5600;
    float acc[25];
    #pragma unroll
    for (int m = 0; m < 25; m++) acc[m] = b5[kq * 25 + m];
    float4 qa[7], qb[7];
    float va, vb;
    load7(wbase, qa); va = cat1T[c];
    for (int j = 0; j < 200; j += 2) {
        load7(wbase + (j + 1) * 28, qb); vb = cat1T[(size_t)(j + 1) * B_ + c];
        fma25(acc, va, qa);
        int j2 = (j + 2 < 200) ? j + 2 : 0;
        load7(wbase + j2 * 28, qa); va = cat1T[(size_t)j2 * B_ + c];
        fma25(acc, vb, qb);
    }
    #pragma unroll
    for (int m = 0; m < 25; m++) h5T[(size_t)(kq * 25 + m) * B_ + c] = acc[m];
}

// ---------------- k2: cross-feature x W7 -> h7Tp[NG] (the compute pillar) ----------------
__global__ __launch_bounds__(64) void k2(const float* __restrict__ h5T, const float* __restrict__ W7fT,
                                         float* __restrict__ h7Tp) {
    int bi = blockIdx.x;
    int g = bi / 512; int r = bi - g * 512;
    int rb = r >> 2, kq = r & 3;
    int lane = threadIdx.x;
    int c = rb * 64 + lane;
    const float* wbase = W7fT + (size_t)kq * NPAIR * 28;
    int p0 = g * PG, p1 = p0 + PG;
    // initial (i,j) for pair p0 (i-major triu enumeration)
    int rem = p0, len = 99;
    while (rem >= len) { rem -= len; len--; }
    int i2 = 99 - len, j2 = i2 + 1 + rem;
    float acc[25];
    #pragma unroll
    for (int m = 0; m < 25; m++) acc[m] = 0.f;
    float4 qa[7], qb[7];
    float hia, hja, hib, hjb;
    load7(wbase + (size_t)p0 * 28, qa);
    hia = h5T[(size_t)i2 * B_ + c]; hja = h5T[(size_t)j2 * B_ + c];
    for (int p = p0; p < p1; p += 2) {
        // pair(p+1) -> buffer B
        j2++; if (j2 >= 100) { i2++; j2 = i2 + 1; }
        load7(wbase + (size_t)(p + 1) * 28, qb);
        hib = h5T[(size_t)i2 * B_ + c]; hjb = h5T[(size_t)j2 * B_ + c];
        float vva = hia * hja;
        fma25(acc, vva, qa);
        // pair(p+2) -> buffer A (clamped dummy on last iteration)
        int pn = p + 2;
        if (pn < p1) { j2++; if (j2 >= 100) { i2++; j2 = i2 + 1; } }
        else pn = p0;
        load7(wbase + (size_t)pn * 28, qa);
        hia = h5T[(size_t)i2 * B_ + c]; hja = h5T[(size_t)j2 * B_ + c];
        float vvb = hib * hjb;
        fma25(acc, vvb, qb);
    }
    float* outp = h7Tp + (size_t)g * 100 * B_;
    #pragma unroll
    for (int m = 0; m < 25; m++) outp[(size_t)(kq * 25 + m) * B_ + c] = acc[m];
}

// ---------------- k3a: h8T = W86 @ h5 + W8b @ h7 + bb8 ----------------
__global__ __launch_bounds__(128) void k3a(const float* __restrict__ h5T, const float* __restrict__ h7Tp,
        const float* __restrict__ W86fT, const float* __restrict__ W8bfT,
        const float* __restrict__ bb8, float* __restrict__ h8T) {
    __shared__ float h7s[100 * 64];
    int rb = blockIdx.x >> 1, kh = blockIdx.x & 1;
    int tid = threadIdx.x, lane = tid & 63, wv = tid >> 6;
    int kq = kh * 2 + wv;
    int r0 = rb * 64, c = r0 + lane;
    // phase 1: sum the NG h7 partials into LDS
    for (int it = 0; it < 50; it++) {
        int o = it * 128 + tid;                     // 6400
        int e = o >> 6, rr = o & 63;
        float s = 0.f;
        #pragma unroll
        for (int g = 0; g < NG; g++) s += h7Tp[((size_t)g * 100 + e) * B_ + r0 + rr];
        h7s[o] = s;
    }
    __syncthreads();
    float acc[25];
    #pragma unroll
    for (int m = 0; m < 25; m++) acc[m] = bb8[kq * 25 + m];
    float4 qa[7], qb[7];
    float va, vb;
    // part 1: h5 (global, coalesced per-lane) x W86
    const float* wb1 = W86fT + kq * 2800;
    load7(wb1, qa); va = h5T[c];
    for (int e = 0; e < 100; e += 2) {
        load7(wb1 + (e + 1) * 28, qb); vb = h5T[(size_t)(e + 1) * B_ + c];
        fma25(acc, va, qa);
        int e2 = (e + 2 < 100) ? e + 2 : 0;
        load7(wb1 + e2 * 28, qa); va = h5T[(size_t)e2 * B_ + c];
        fma25(acc, vb, qb);
    }
    // part 2: h7 (LDS, lgkm does not mix with vmcnt) x W8b
    const float* wb2 = W8bfT + kq * 2800;
    load7(wb2, qa); va = h7s[lane];
    for (int e = 0; e < 100; e += 2) {
        load7(wb2 + (e + 1) * 28, qb); vb = h7s[(e + 1) * 64 + lane];
        fma25(acc, va, qa);
        int e2 = (e + 2 < 100) ? e + 2 : 0;
        load7(wb2 + e2 * 28, qa); va = h7s[e2 * 64 + lane];
        fma25(acc, vb, qb);
    }
    #pragma unroll
    for (int m = 0; m < 25; m++) h8T[(size_t)(kq * 25 + m) * B_ + c] = acc[m];
}

// ---------------- k3b: out = h8 @ label_embedding (bias pre-folded into h8T) ----------------
__global__ __launch_bounds__(256) void k3b(const float* __restrict__ h8T, const float* __restrict__ le,
                                           float* __restrict__ out) {
    int lq = blockIdx.x & 3, bb = blockIdx.x >> 2;
    int b0 = bb * 32;
    int l = lq * 256 + threadIdx.x;
    bool valid = (l < L_);
    int lc = valid ? l : 0;
    float acc[32];
    #pragma unroll
    for (int ii = 0; ii < 32; ii++) acc[ii] = 0.f;
    float4 qa[8], qb[8];
    float va, vb;
    load8(h8T + b0, qa); va = le[lc];
    for (int u = 0; u < 100; u += 2) {
        load8(h8T + (size_t)(u + 1) * B_ + b0, qb); vb = le[(u + 1) * 1000 + lc];
        fma32(acc, va, qa);
        int u2 = (u + 2 < 100) ? u + 2 : 0;
        load8(h8T + (size_t)u2 * B_ + b0, qa); va = le[u2 * 1000 + lc];
        fma32(acc, vb, qb);
    }
    if (valid) {
        #pragma unroll
        for (int ii = 0; ii < 32; ii++)
            out[(size_t)(b0 + ii) * 1000 + l] = acc[ii];
    }
}

extern "C" void kernel_launch(void* const* d_in, const int* in_sizes, int n_in,
                              void* d_out, int out_size, void* d_ws, size_t ws_size,
                              hipStream_t stream) {
    const float* x  = (const float*)d_in[0];
    const float* v  = (const float*)d_in[1];
    const float* W1 = (const float*)d_in[2];
    const float* b1 = (const float*)d_in[3];
    const float* W2 = (const float*)d_in[4];
    const float* W3 = (const float*)d_in[5];
    const float* b3 = (const float*)d_in[6];
    const float* W4 = (const float*)d_in[7];
    const float* W5 = (const float*)d_in[8];
    const float* b5 = (const float*)d_in[9];
    const float* W6 = (const float*)d_in[10];
    const float* b6 = (const float*)d_in[11];
    const float* W7 = (const float*)d_in[12];
    const float* b7 = (const float*)d_in[13];
    const float* W8 = (const float*)d_in[14];
    const float* b8 = (const float*)d_in[15];
    const float* le = (const float*)d_in[16];
    float* out = (float*)d_out;
    float* ws = (float*)d_ws;

    // layout (floats). cat1T aliases h7Tp: cat1T dead before k2 writes h7Tp.
    float* h7Tp  = ws;                    // NG*100*B = 4,096,000
    float* cat1T = ws;                    // 200*B    = 1,638,400 (alias)
    float* h5T   = ws + 4096000;          // 819,200
    float* h8T   = ws + 4915200;          // 819,200
    float* W7fT  = ws + 5734400;          // 4*4950*28 = 554,400
    float* W5fT  = ws + 6288800;          // 22,400
    float* W86fT = ws + 6311200;          // 11,200
    float* W8bfT = ws + 6322400;          // 11,200
    float* usf   = ws + 6333600;          // 200
    float* csf   = ws + 6333800;          // 2 (+2 pad)
    float* bb8   = ws + 6333804;          // 100

    k0<<<255, 256, 0, stream>>>(v, W1, b1, W2, W3, b3, W4, W5, W6, W7, b6, b7, W8, b8,
                                W7fT, W5fT, W86fT, W8bfT, usf, csf, bb8);
    k1<<<8192, 256, 0, stream>>>(x, usf, csf, cat1T);
    k15<<<512, 64, 0, stream>>>(cat1T, W5fT, b5, h5T);
    k2<<<2560, 64, 0, stream>>>(h5T, W7fT, h7Tp);
    k3a<<<256, 128, 0, stream>>>(h5T, h7Tp, W86fT, W8bfT, bb8, h8T);
    k3b<<<1024, 256, 0, stream>>>(h8T, le, out);
}

// Round 4
// 1012.759 us; speedup vs baseline: 1.0139x; 1.0139x over previous
//
#include <hip/hip_runtime.h>
#include <cstdint>
#include <cstddef>

#define B_    8192
#define L_    1000
#define NPAIR 4950

// Opaque zero that lives in a VGPR. Adding it to an address makes the address
// lane-varying as far as the compiler can prove -> forces per-lane VMEM loads
// (global_load_dwordx4, in-order vmcnt) instead of s_load + lgkmcnt(0) drains,
// which serialized rounds 2 and 3 (k2 VGPR_Count=36 proved regs never held data).
__device__ __forceinline__ int lane_zero() {
    int z = 0;
    asm volatile("" : "+v"(z));
    return z;
}

__device__ __forceinline__ void load7(const float* p, float4 q[7]) {
    const float4* p4 = (const float4*)p;
    #pragma unroll
    for (int t = 0; t < 7; t++) q[t] = p4[t];
}

// acc[25][4] += w[0..24] (x) cf[0..3]
__device__ __forceinline__ void fma100(float acc[25][4], float4 cf, const float4 q[7]) {
    const float* w = (const float*)q;
    #pragma unroll
    for (int m = 0; m < 25; m++) {
        acc[m][0] = fmaf(w[m], cf.x, acc[m][0]);
        acc[m][1] = fmaf(w[m], cf.y, acc[m][1]);
        acc[m][2] = fmaf(w[m], cf.z, acc[m][2]);
        acc[m][3] = fmaf(w[m], cf.w, acc[m][3]);
    }
}

// ---------------- k0: all weight prep in ONE launch (255 blocks) ----------------
__global__ __launch_bounds__(256) void k0(const float* __restrict__ v,
        const float* __restrict__ W1, const float* __restrict__ b1, const float* __restrict__ W2,
        const float* __restrict__ W3, const float* __restrict__ b3, const float* __restrict__ W4,
        const float* __restrict__ W5, const float* __restrict__ W6, const float* __restrict__ W7,
        const float* __restrict__ b6, const float* __restrict__ b7,
        const float* __restrict__ W8, const float* __restrict__ b8,
        float* __restrict__ W7fT, float* __restrict__ W5fT, float* __restrict__ W86fT,
        float* __restrict__ W8bfT, float* __restrict__ usf, float* __restrict__ csf,
        float* __restrict__ bb8) {
    int blk = blockIdx.x, tid = threadIdx.x;
    if (blk < 78) {
        // W7fT[kq][p][28] = W7[kq*25+m][p] * vv(p); 64 pairs per block
        int p0 = blk * 64;
        for (int it = 0; it < 25; it++) {
            int o = it * 256 + tid;                  // 64*100
            int pl = o / 100, k = o - pl * 100;
            int p = p0 + pl;
            if (p < NPAIR) {
                int rem = p, len = 99;
                while (rem >= len) { rem -= len; len--; }
                int i = 99 - len; int j = i + 1 + rem;
                float vv = v[i*4+0]*v[j*4+0] + v[i*4+1]*v[j*4+1]
                         + v[i*4+2]*v[j*4+2] + v[i*4+3]*v[j*4+3];
                int kq = k / 25, m = k - kq * 25;
                W7fT[((size_t)kq * NPAIR + p) * 28 + m] = W7[(size_t)k * NPAIR + p] * vv;
            }
        }
    } else if (blk < 166) {
        // W5fT[kq][j][28] = W5[kq*25+m][j]
        int o = (blk - 78) * 256 + tid;              // 4*200*28 = 22400
        if (o < 22400) {
            int kq = o / 5600; int r = o - kq * 5600; int j = r / 28; int m = r - j * 28;
            W5fT[o] = (m < 25) ? W5[(kq * 25 + m) * 200 + j] : 0.f;
        }
    } else if (blk < 210) {
        // W86fT[kq][e][28] = sum_e2 W8[u][e2]*W6[e2][e],  u = kq*25+m
        int o = (blk - 166) * 256 + tid;             // 4*100*28 = 11200
        if (o < 11200) {
            int kq = o / 2800; int r = o - kq * 2800; int e = r / 28; int m = r - e * 28;
            float s = 0.f;
            if (m < 25) {
                int u = kq * 25 + m;
                for (int e2 = 0; e2 < 100; e2++) s = fmaf(W8[u * 200 + e2], W6[e2 * 100 + e], s);
            }
            W86fT[o] = s;
        }
    } else if (blk < 254) {
        // W8bfT[kq][e][28] = W8[kq*25+m][100+e]
        int o = (blk - 210) * 256 + tid;
        if (o < 11200) {
            int kq = o / 2800; int r = o - kq * 2800; int e = r / 28; int m = r - e * 28;
            W8bfT[o] = (m < 25) ? W8[(kq * 25 + m) * 200 + 100 + e] : 0.f;
        }
    } else {
        if (tid < 200) {
            int h = (tid >= 100); int e = tid - 100 * h;
            const float* Wa = h ? W3 : W1; const float* Wb = h ? W4 : W2;
            float u = 0.f;
            for (int t = 0; t < 8; t++) u += Wa[t * 100 + e] * Wb[t];
            usf[tid] = u;
        } else if (tid < 202) {
            int h = tid - 200;
            const float* bbv = h ? b3 : b1; const float* Wb = h ? W4 : W2;
            float c = 0.f;
            for (int t = 0; t < 8; t++) c += bbv[t] * Wb[t];
            csf[h] = c;
        }
        if (tid < 100) {
            // bb8[u] = b8[u] + W8a@b6 + W8b@b7
            float s = b8[tid];
            for (int e = 0; e < 100; e++)
                s = fmaf(W8[tid * 200 + e], b6[e], fmaf(W8[tid * 200 + 100 + e], b7[e], s));
            bb8[tid] = s;
        }
    }
}

// ---------------- k1: attention pools -> cat1T[200][B] ----------------
__global__ __launch_bounds__(256) void k1(const float* __restrict__ x, const float* __restrict__ usf,
                                          const float* __restrict__ csf, float* __restrict__ cat1T) {
    __shared__ float xs[50 * 101];
    __shared__ float uss[200];
    __shared__ float part[256];
    __shared__ float zs[2][64];
    __shared__ float wsm[2][64];
    __shared__ float css[2];
    int b = blockIdx.x, tid = threadIdx.x;
    const float* xr = x + (size_t)b * 5000;
    for (int li = tid; li < 1250; li += 256) {
        float4 q = ((const float4*)xr)[li];
        int flat = li * 4; int n = flat / 100, e = flat - n * 100;
        float* d = xs + n * 101 + e;
        d[0] = q.x; d[1] = q.y; d[2] = q.z; d[3] = q.w;
    }
    if (tid < 200) uss[tid] = usf[tid];
    if (tid < 2) css[tid] = csf[tid];
    __syncthreads();
    if (tid < 200) {
        int h = tid & 1, q = (tid >> 1) & 1, n = tid >> 2;
        const float* u = uss + h * 100 + q * 50;
        const float* xv = xs + n * 101 + q * 50;
        float s = 0.f;
        for (int e = 0; e < 50; e++) s = fmaf(xv[e], u[e], s);
        part[tid] = s;
    }
    __syncthreads();
    if (tid < 100) {
        int h = tid & 1, n = tid >> 1;
        float z = css[h] + part[(n << 2) | h] + part[(n << 2) | 2 | h];
        zs[h][n] = expf(z);                         // logits = exp(h @ Wb^T)
    }
    __syncthreads();
    int wv = tid >> 6, ln = tid & 63;
    if (wv < 2) {
        float a = (ln < 50) ? zs[wv][ln] : -3.0e38f;
        float m = a;
        for (int s = 1; s < 64; s <<= 1) m = fmaxf(m, __shfl_xor(m, s, 64));
        float ex = (ln < 50) ? expf(a - m) : 0.f;
        float ss = ex;
        for (int s = 1; s < 64; s <<= 1) ss += __shfl_xor(ss, s, 64);
        if (ln < 50) wsm[wv][ln] = ex / ss;         // softmax over N of the logits
    }
    __syncthreads();
    if (tid < 200) {
        int h = (tid >= 100); int e = tid - 100 * h;
        const float* wp = wsm[h];
        float s = 0.f;
        for (int n = 0; n < 50; n++) s = fmaf(xs[n * 101 + e], wp[n], s);
        cat1T[(size_t)tid * B_ + b] = s;            // transposed for downstream coalescing
    }
}

// ---------------- k15: h5T = W5 @ cat1 + b5 (25k x 4b tiles, j-split x4, atomic) --------
__global__ __launch_bounds__(64, 2) void k15(const float* __restrict__ cat1T,
        const float* __restrict__ W5fT, const float* __restrict__ b5, float* __restrict__ h5T) {
    int blk = blockIdx.x;
    int bt = blk >> 4, kq = (blk >> 2) & 3, jg = blk & 3;
    int lane = threadIdx.x;
    int z = lane_zero();
    int c = bt * 256 + lane * 4;
    const float4* av = (const float4*)(cat1T + c);     // av[j*2048] = cat1T[j][c..c+3]
    const float* wb = W5fT + kq * 5600 + z;
    int j0 = jg * 50, j1 = j0 + 50;
    float acc[25][4];
    #pragma unroll
    for (int m = 0; m < 25; m++) { acc[m][0]=0.f; acc[m][1]=0.f; acc[m][2]=0.f; acc[m][3]=0.f; }
    float4 qa[7], qb[7];
    float4 aa, ab;
    load7(wb + j0 * 28, qa); aa = av[(size_t)j0 * 2048];
    for (int j = j0; j < j1; j += 2) {
        load7(wb + (j + 1) * 28, qb); ab = av[(size_t)(j + 1) * 2048];
        fma100(acc, aa, qa);
        int jn = (j + 2 < j1) ? j + 2 : j0;
        load7(wb + jn * 28, qa); aa = av[(size_t)jn * 2048];
        fma100(acc, ab, qb);
    }
    if (jg == 0) {
        #pragma unroll
        for (int m = 0; m < 25; m++) {
            float bv = *(b5 + kq * 25 + m + z);
            acc[m][0] += bv; acc[m][1] += bv; acc[m][2] += bv; acc[m][3] += bv;
        }
    }
    float* op = h5T + (size_t)(kq * 25) * B_ + c;
    #pragma unroll
    for (int m = 0; m < 25; m++) {
        atomicAdd(op + (size_t)m * B_ + 0, acc[m][0]);
        atomicAdd(op + (size_t)m * B_ + 1, acc[m][1]);
        atomicAdd(op + (size_t)m * B_ + 2, acc[m][2]);
        atomicAdd(op + (size_t)m * B_ + 3, acc[m][3]);
    }
}

// ---------------- k2: cross-feature x W7 (25k x 4b tiles, pair-split x16, atomic) --------
__global__ __launch_bounds__(64, 2) void k2(const float* __restrict__ h5T,
        const float* __restrict__ W7fT, float* __restrict__ h7T) {
    int blk = blockIdx.x;
    int bt = blk >> 6, kq = (blk >> 4) & 3, pg = blk & 15;
    int lane = threadIdx.x;
    int z = lane_zero();
    int c = bt * 256 + lane * 4;
    const float4* h5v = (const float4*)(h5T + c);      // h5v[e*2048] = h5T[e][c..c+3]
    const float* wb = W7fT + (size_t)kq * (NPAIR * 28) + z;
    int p0 = pg * 310;
    int p1 = min(NPAIR, p0 + 310);                     // last group: 300, all even
    // (i,j) for pair p0 (i-major triu, k=1)
    int rem = p0, len = 99;
    while (rem >= len) { rem -= len; len--; }
    int i = 99 - len, j = i + 1 + rem;
    float acc[25][4];
    #pragma unroll
    for (int m = 0; m < 25; m++) { acc[m][0]=0.f; acc[m][1]=0.f; acc[m][2]=0.f; acc[m][3]=0.f; }
    float4 qa[7], qb[7];
    float4 hia, hja, hib, hjb;
    load7(wb + (size_t)p0 * 28, qa);
    hia = h5v[(size_t)i * 2048]; hja = h5v[(size_t)j * 2048];
    for (int p = p0; p < p1; p += 2) {
        // pair p+1 -> buffer B
        int i1 = i, j1 = j + 1; if (j1 >= 100) { i1++; j1 = i1 + 1; }
        load7(wb + (size_t)(p + 1) * 28, qb);
        hib = h5v[(size_t)i1 * 2048]; hjb = h5v[(size_t)j1 * 2048];
        float4 cfa; cfa.x = hia.x*hja.x; cfa.y = hia.y*hja.y; cfa.z = hia.z*hja.z; cfa.w = hia.w*hja.w;
        fma100(acc, cfa, qa);
        // pair p+2 -> buffer A (dummy = p0 on last iter)
        int i2 = i1, j2 = j1 + 1; if (j2 >= 100) { i2++; j2 = i2 + 1; }
        int pn = p + 2;
        if (pn >= p1) { pn = p0; i2 = 0; j2 = 1; }
        load7(wb + (size_t)pn * 28, qa);
        hia = h5v[(size_t)i2 * 2048]; hja = h5v[(size_t)j2 * 2048];
        i = i2; j = j2;
        float4 cfb; cfb.x = hib.x*hjb.x; cfb.y = hib.y*hjb.y; cfb.z = hib.z*hjb.z; cfb.w = hib.w*hjb.w;
        fma100(acc, cfb, qb);
    }
    float* op = h7T + (size_t)(kq * 25) * B_ + c;
    #pragma unroll
    for (int m = 0; m < 25; m++) {
        atomicAdd(op + (size_t)m * B_ + 0, acc[m][0]);
        atomicAdd(op + (size_t)m * B_ + 1, acc[m][1]);
        atomicAdd(op + (size_t)m * B_ + 2, acc[m][2]);
        atomicAdd(op + (size_t)m * B_ + 3, acc[m][3]);
    }
}

// ---------------- k3a: h8T = W86@h5 + W8b@h7 + bb8 (K-split x4, atomic) ----------------
__global__ __launch_bounds__(64, 2) void k3a(const float* __restrict__ h5T,
        const float* __restrict__ h7T, const float* __restrict__ W86fT,
        const float* __restrict__ W8bfT, const float* __restrict__ bb8, float* __restrict__ h8T) {
    int blk = blockIdx.x;
    int bt = blk >> 4, uq = (blk >> 2) & 3, Kg = blk & 3;
    int lane = threadIdx.x;
    int z = lane_zero();
    int c = bt * 256 + lane * 4;
    const float* act; const float* wb0;
    if (Kg < 2) { act = h5T + (size_t)(Kg * 50) * B_;      wb0 = W86fT + uq * 2800 + Kg * 50 * 28; }
    else        { act = h7T + (size_t)((Kg - 2) * 50) * B_; wb0 = W8bfT + uq * 2800 + (Kg - 2) * 50 * 28; }
    const float* wb = wb0 + z;
    const float4* av = (const float4*)(act + c);
    float acc[25][4];
    #pragma unroll
    for (int m = 0; m < 25; m++) { acc[m][0]=0.f; acc[m][1]=0.f; acc[m][2]=0.f; acc[m][3]=0.f; }
    float4 qa[7], qb[7];
    float4 aa, ab;
    load7(wb, qa); aa = av[0];
    for (int e = 0; e < 50; e += 2) {
        load7(wb + (e + 1) * 28, qb); ab = av[(size_t)(e + 1) * 2048];
        fma100(acc, aa, qa);
        int en = (e + 2 < 50) ? e + 2 : 0;
        load7(wb + en * 28, qa); aa = av[(size_t)en * 2048];
        fma100(acc, ab, qb);
    }
    if (Kg == 0) {
        #pragma unroll
        for (int m = 0; m < 25; m++) {
            float bv = *(bb8 + uq * 25 + m + z);
            acc[m][0] += bv; acc[m][1] += bv; acc[m][2] += bv; acc[m][3] += bv;
        }
    }
    float* op = h8T + (size_t)(uq * 25) * B_ + c;
    #pragma unroll
    for (int m = 0; m < 25; m++) {
        atomicAdd(op + (size_t)m * B_ + 0, acc[m][0]);
        atomicAdd(op + (size_t)m * B_ + 1, acc[m][1]);
        atomicAdd(op + (size_t)m * B_ + 2, acc[m][2]);
        atomicAdd(op + (size_t)m * B_ + 3, acc[m][3]);
    }
}

// ---------------- k3b: out = h8 @ le (32b x 128l per wave) ----------------
__global__ __launch_bounds__(64, 2) void k3b(const float* __restrict__ h8T,
        const float* __restrict__ le, float* __restrict__ out) {
    int blk = blockIdx.x;
    int bt = blk >> 3, lt = blk & 7;
    int lane = threadIdx.x;
    int z = lane_zero();
    int b0 = bt * 32;
    int l = lt * 128 + lane * 2;
    bool valid = (l < L_);
    int lc = valid ? l : 0;
    const float* h8b = h8T + b0 + z;                  // lane-shared addresses (bcast)
    const float2* lep = (const float2*)(le + lc);     // per-lane; lep[u*500] = le[u][l..l+1]
    float acc[32][2];
    #pragma unroll
    for (int t = 0; t < 32; t++) { acc[t][0] = 0.f; acc[t][1] = 0.f; }
    float4 qa[8], qb[8];
    float2 lea, leb;
    #pragma unroll
    for (int t = 0; t < 8; t++) qa[t] = ((const float4*)h8b)[t];
    lea = lep[0];
    for (int u = 0; u < 100; u += 2) {
        const float4* pb = (const float4*)(h8b + (size_t)(u + 1) * B_);
        #pragma unroll
        for (int t = 0; t < 8; t++) qb[t] = pb[t];
        leb = lep[(size_t)(u + 1) * 500];
        const float* ha = (const float*)qa;
        #pragma unroll
        for (int t = 0; t < 32; t++) {
            acc[t][0] = fmaf(ha[t], lea.x, acc[t][0]);
            acc[t][1] = fmaf(ha[t], lea.y, acc[t][1]);
        }
        int un = (u + 2 < 100) ? u + 2 : 0;
        const float4* pa = (const float4*)(h8b + (size_t)un * B_);
        #pragma unroll
        for (int t = 0; t < 8; t++) qa[t] = pa[t];
        lea = lep[(size_t)un * 500];
        const float* hb = (const float*)qb;
        #pragma unroll
        for (int t = 0; t < 32; t++) {
            acc[t][0] = fmaf(hb[t], leb.x, acc[t][0]);
            acc[t][1] = fmaf(hb[t], leb.y, acc[t][1]);
        }
    }
    if (valid) {
        #pragma unroll
        for (int t = 0; t < 32; t++) {
            float2 o2; o2.x = acc[t][0]; o2.y = acc[t][1];
            *((float2*)(out + (size_t)(b0 + t) * 1000 + l)) = o2;
        }
    }
}

extern "C" void kernel_launch(void* const* d_in, const int* in_sizes, int n_in,
                              void* d_out, int out_size, void* d_ws, size_t ws_size,
                              hipStream_t stream) {
    const float* x  = (const float*)d_in[0];
    const float* v  = (const float*)d_in[1];
    const float* W1 = (const float*)d_in[2];
    const float* b1 = (const float*)d_in[3];
    const float* W2 = (const float*)d_in[4];
    const float* W3 = (const float*)d_in[5];
    const float* b3 = (const float*)d_in[6];
    const float* W4 = (const float*)d_in[7];
    const float* W5 = (const float*)d_in[8];
    const float* b5 = (const float*)d_in[9];
    const float* W6 = (const float*)d_in[10];
    const float* b6 = (const float*)d_in[11];
    const float* W7 = (const float*)d_in[12];
    const float* b7 = (const float*)d_in[13];
    const float* W8 = (const float*)d_in[14];
    const float* b8 = (const float*)d_in[15];
    const float* le = (const float*)d_in[16];
    float* out = (float*)d_out;
    float* ws = (float*)d_ws;

    float* cat1T = ws;                    // 1,638,400
    float* h5T   = ws + 1638400;          //   819,200
    float* h7T   = ws + 2457600;          //   819,200
    float* h8T   = ws + 3276800;          //   819,200
    float* W7fT  = ws + 4096000;          //   554,400
    float* W5fT  = ws + 4650400;          //    22,400
    float* W86fT = ws + 4672800;          //    11,200
    float* W8bfT = ws + 4684000;          //    11,200
    float* usf   = ws + 4695200;          //       200
    float* csf   = ws + 4695400;          //       4
    float* bb8   = ws + 4695404;          //       100

    hipMemsetAsync(h5T, 0, (size_t)819200 * 4, stream);
    hipMemsetAsync(h7T, 0, (size_t)819200 * 4, stream);
    hipMemsetAsync(h8T, 0, (size_t)819200 * 4, stream);

    k0<<<255, 256, 0, stream>>>(v, W1, b1, W2, W3, b3, W4, W5, W6, W7, b6, b7, W8, b8,
                                W7fT, W5fT, W86fT, W8bfT, usf, csf, bb8);
    k1<<<8192, 256, 0, stream>>>(x, usf, csf, cat1T);
    k15<<<512, 64, 0, stream>>>(cat1T, W5fT, b5, h5T);
    k2<<<2048, 64, 0, stream>>>(h5T, W7fT, h7T);
    k3a<<<512, 64, 0, stream>>>(h5T, h7T, W86fT, W8bfT, bb8, h8T);
    k3b<<<2048, 64, 0, stream>>>(h8T, le, out);
}